// Round 11
// baseline (481.429 us; speedup 1.0000x reference)
//
#include <hip/hip_runtime.h>
#include <hip/hip_bf16.h>
#include <stdint.h>

#define CH 256
#define D8 32
#define NN 4096

typedef __attribute__((ext_vector_type(8))) short short8;
typedef __attribute__((ext_vector_type(4))) short s16x4;
typedef __attribute__((ext_vector_type(4))) float f32x4;

#define MFMA16(a,b,c) __builtin_amdgcn_mfma_f32_16x16x32_bf16(a,b,c,0,0,0)
// lgkm-only barrier: orders LDS producer/consumer WITHOUT draining vmcnt --
// global K/V prefetches stay in flight across chunk boundaries (T4).
#define BAR() asm volatile("s_waitcnt lgkmcnt(0)\n\ts_barrier" ::: "memory")

static __device__ __forceinline__ short f2bf(float f) {
  union { float f; uint32_t u; } v; v.f = f;
  uint32_t r = v.u + 0x7fffu + ((v.u >> 16) & 1u);
  return (short)(r >> 16);
}
static __device__ __forceinline__ float bf2f(short h) {
  union { float f; uint32_t u; } v; v.u = ((uint32_t)(uint16_t)h) << 16;
  return v.f;
}
static __device__ __forceinline__ int f2i(float f) {
  union { float f; int i; } v; v.f = f; return v.i;
}
static __device__ __forceinline__ float i2f(int i) {
  union { float f; int i; } v; v.i = i; return v.f;
}

// DPP 16-lane-row reductions (VALU latency, no LDS)
#define DPP_MAX16(V) do { \
    V = fmaxf(V, i2f(__builtin_amdgcn_update_dpp(0, f2i(V), 0xB1, 0xf, 0xf, true)));  \
    V = fmaxf(V, i2f(__builtin_amdgcn_update_dpp(0, f2i(V), 0x4E, 0xf, 0xf, true)));  \
    V = fmaxf(V, i2f(__builtin_amdgcn_update_dpp(0, f2i(V), 0x124, 0xf, 0xf, true))); \
    V = fmaxf(V, i2f(__builtin_amdgcn_update_dpp(0, f2i(V), 0x128, 0xf, 0xf, true))); \
  } while (0)
#define DPP_SUM16(V) do { \
    V += i2f(__builtin_amdgcn_update_dpp(0, f2i(V), 0xB1, 0xf, 0xf, true));  \
    V += i2f(__builtin_amdgcn_update_dpp(0, f2i(V), 0x4E, 0xf, 0xf, true));  \
    V += i2f(__builtin_amdgcn_update_dpp(0, f2i(V), 0x124, 0xf, 0xf, true)); \
    V += i2f(__builtin_amdgcn_update_dpp(0, f2i(V), 0x128, 0xf, 0xf, true)); \
  } while (0)

// ---------------- prep_x: x (b,c,n) fp32 -> xT (b,n,c) bf16 ----------------
__global__ __launch_bounds__(256) void prep_x(
    const float* __restrict__ x, short* __restrict__ xT)
{
  int blk = blockIdx.x, t = threadIdx.x;
  int b = blk >> 8, ct = (blk >> 6) & 3, nt = blk & 63;
  __shared__ short T[64][65];                    // +1 pad: conflict-free transpose
  int i0 = t >> 4, j4 = (t & 15) * 4;
  const float* xb = x + ((size_t)b * CH + ct * 64) * NN + nt * 64;
  #pragma unroll
  for (int p = 0; p < 4; ++p) {
    int i = i0 + p * 16;
    float4 v = *(const float4*)(xb + (size_t)i * NN + j4);
    T[i][j4 + 0] = f2bf(v.x); T[i][j4 + 1] = f2bf(v.y);
    T[i][j4 + 2] = f2bf(v.z); T[i][j4 + 3] = f2bf(v.w);
  }
  __syncthreads();
  int n = t & 63, c80 = t >> 6;
  short* xTb = xT + ((size_t)b * NN + nt * 64 + n) * CH + ct * 64;
  #pragma unroll
  for (int p = 0; p < 2; ++p) {
    int c8 = c80 + p * 4;
    short8 v;
    #pragma unroll
    for (int k = 0; k < 8; ++k) v[k] = T[c8 * 8 + k][n];
    *(short8*)(xTb + c8 * 8) = v;
  }
}

// ---------------- prep_w: weight convert (64 blocks) ----------------
__global__ __launch_bounds__(256) void prep_w(
    const float* __restrict__ wq, const float* __restrict__ bq,
    const float* __restrict__ wk, const float* __restrict__ bk,
    const float* __restrict__ wv, const float* __restrict__ bv,
    short* __restrict__ WQb, short* __restrict__ WKb, short* __restrict__ WVb,
    float* __restrict__ BQ, float* __restrict__ BK, float* __restrict__ BV)
{
  int idx = blockIdx.x * 256 + threadIdx.x;
  const float LOG2E = 1.4426950408889634f;       // fold into Q so exp2 == exp
  for (int i = idx; i < D8 * CH; i += 16384) WQb[i] = f2bf(wq[i] * LOG2E);
  for (int i = idx; i < D8 * CH; i += 16384) WKb[i] = f2bf(wk[i]);
  for (int i = idx; i < CH * CH; i += 16384) WVb[i] = f2bf(wv[i]);
  if (idx < D8) { BQ[idx] = bq[idx] * LOG2E; BK[idx] = bk[idx]; }
  if (idx < CH) BV[idx] = bv[idx];
}

// ---------------- proj: 1024 blocks (4/CU), 16 pos/block, 5 tiles/wave, prefetched ----------------
__global__ __launch_bounds__(256) void proj_kernel(
    const short* __restrict__ xT,
    const short* __restrict__ WQb, const short* __restrict__ WKb,
    const short* __restrict__ WVb,
    const float* __restrict__ BQ, const float* __restrict__ BK,
    const float* __restrict__ BV,
    short* __restrict__ Qh, short* __restrict__ Ql,
    short* __restrict__ Kh, short* __restrict__ Kl,
    short* __restrict__ Vo)
{
  int blk = blockIdx.x, t = threadIdx.x;
  int b = blk >> 8, pt = blk & 255;
  int w = t >> 6, lane = t & 63, g = lane >> 4, lr = lane & 15;
  int p0 = pt * 16;
  __shared__ short Vt[4][16][20];

  const short* xrow = xT + ((size_t)b * NN + p0 + lr) * CH + g * 8;
  short8 a[8];
  #pragma unroll
  for (int s = 0; s < 8; ++s) a[s] = *(const short8*)(xrow + s * 32);

  const f32x4 zf = {0.f, 0.f, 0.f, 0.f};

#define WLOAD(DST, TT) do { \
    const short* _W; int _tl; \
    if ((TT) < 2)      { _W = WQb; _tl = (TT); } \
    else if ((TT) < 4) { _W = WKb; _tl = (TT) - 2; } \
    else               { _W = WVb; _tl = (TT) - 4; } \
    _Pragma("unroll") \
    for (int s = 0; s < 8; ++s) \
      DST[s] = *(const short8*)(_W + (size_t)(_tl * 16 + lr) * CH + s * 32 + g * 8); \
  } while (0)

#define WCOMP(CUR, TT) do { \
    int _tloc; const float* _Bs; \
    if ((TT) < 2)      { _Bs = BQ; _tloc = (TT); } \
    else if ((TT) < 4) { _Bs = BK; _tloc = (TT) - 2; } \
    else               { _Bs = BV; _tloc = (TT) - 4; } \
    f32x4 acc = zf; \
    _Pragma("unroll") \
    for (int s = 0; s < 8; ++s) acc = MFMA16(a[s], CUR[s], acc); \
    int o = _tloc * 16 + lr; \
    float bias = _Bs[o]; \
    if ((TT) < 4) { \
      short* Oh = ((TT) < 2) ? Qh : Kh; \
      short* Ol = ((TT) < 2) ? Ql : Kl; \
      _Pragma("unroll") \
      for (int r = 0; r < 4; ++r) { \
        int pos = p0 + g * 4 + r; \
        float val = acc[r] + bias; \
        short hi = f2bf(val); \
        Oh[((size_t)b * NN + pos) * D8 + o] = hi; \
        Ol[((size_t)b * NN + pos) * D8 + o] = f2bf(val - bf2f(hi)); \
      } \
    } else { \
      _Pragma("unroll") \
      for (int r = 0; r < 4; ++r) \
        Vt[w][lr][g * 4 + r] = f2bf(acc[r] + bias); \
      int row = lane >> 2, c4 = (lane & 3) * 4; \
      s16x4 vv = *(const s16x4*)&Vt[w][row][c4]; \
      *(s16x4*)(Vo + ((size_t)b * CH + _tloc * 16 + row) * NN + p0 + c4) = vv; \
    } \
  } while (0)

  int t0 = w * 5;
  short8 bA[8], bB[8];
  WLOAD(bA, t0);
  WLOAD(bB, t0 + 1); WCOMP(bA, t0);
  WLOAD(bA, t0 + 2); WCOMP(bB, t0 + 1);
  WLOAD(bB, t0 + 3); WCOMP(bA, t0 + 2);
  WLOAD(bA, t0 + 4); WCOMP(bB, t0 + 3);
  WCOMP(bA, t0 + 4);
#undef WLOAD
#undef WCOMP
}

// ---- attn: 32 q/block, 512 blocks (2 independent blocks/CU), r6 sync flow ----
// waves 0,1: S(16q each)+PV; waves 2-7: PV-only. All waves PV 32ch.
__global__ __launch_bounds__(512, 4) void attn_kernel(
    const short* __restrict__ Qh, const short* __restrict__ Ql,
    const short* __restrict__ Kh, const short* __restrict__ Kl,
    const short* __restrict__ V, const float* __restrict__ x,
    float* __restrict__ out)
{
  int blk = blockIdx.x, t = threadIdx.x;
  // XCD swizzle: 2 XCDs per batch -> per-batch K+V stay L2-resident
  int xcd = blk & 7, idx = blk >> 3;             // idx 0..63
  int b = xcd >> 1;
  int qt = ((xcd & 1) << 6) + idx;               // 0..127
  int q0 = qt * 32;
  int w = t >> 6, lane = t & 63, g = lane >> 4, lr = lane & 15;
  int wS = w;                                    // valid for w<2
  bool isS = (w < 2);
  int cw0 = w * 32;                              // 8 waves x 32 channels

  union Smem {
    struct {
      short P[2][32 * 64];                       // double-buffered, XOR-swizzled
      float scale[2][32];
      int   flags[2][2];
    } lp;
    float O[CH][33];                             // epilogue transpose buffer
  };
  __shared__ Smem sm;
  __shared__ float l_lds[32];

  const short* Qhb = Qh + (size_t)b * NN * D8;
  const short* Qlb = Ql + (size_t)b * NN * D8;
  const short* Khb = Kh + (size_t)b * NN * D8;
  const short* Klb = Kl + (size_t)b * NN * D8;
  const short* Vb = V + (size_t)b * CH * NN;

  short8 aqh, aql;
  if (isS) {
    aqh = *(const short8*)(Qhb + (size_t)(q0 + wS * 16 + lr) * D8 + g * 8);
    aql = *(const short8*)(Qlb + (size_t)(q0 + wS * 16 + lr) * D8 + g * 8);
  }

  const f32x4 zf = {0.f, 0.f, 0.f, 0.f};
  f32x4 O[2][2];                                 // 32q x 32ch per wave
  #pragma unroll
  for (int i = 0; i < 2; ++i)
    #pragma unroll
    for (int j = 0; j < 2; ++j) O[i][j] = zf;
  float m[4] = {-INFINITY, -INFINITY, -INFINITY, -INFINITY};
  float l[4] = {0.f, 0.f, 0.f, 0.f};

  char* Pbase0 = (char*)&sm.lp.P[0][0];
  char* Pbase1 = (char*)&sm.lp.P[1][0];

#define LOADK(KH, KL, KIDX) do { \
    int _k0 = ((KIDX) & 63) * 64; \
    _Pragma("unroll") \
    for (int _nt = 0; _nt < 4; ++_nt) { \
      size_t _off = (size_t)(_k0 + _nt * 16 + lr) * D8 + g * 8; \
      KH[_nt] = *(const short8*)(Khb + _off); \
      KL[_nt] = *(const short8*)(Klb + _off); \
    } \
  } while (0)

#define LOADV(VV, KIDX) do { \
    int _k0 = ((KIDX) & 63) * 64; \
    _Pragma("unroll") \
    for (int _ss = 0; _ss < 2; ++_ss) \
      _Pragma("unroll") \
      for (int _ci = 0; _ci < 2; ++_ci) \
        VV[_ss * 2 + _ci] = *(const short8*)(Vb + \
            (size_t)(cw0 + _ci * 16 + lr) * NN + _k0 + _ss * 32 + g * 8); \
  } while (0)

  // STEP: S waves produce+publish chunk KB (prefetch K,V for KB+1);
  // PV-only waves prefetch V; BAR; ALL waves PV-consume chunk KB from regs VV.
#define STEP(KB, KH, KL, VV, NKH, NKL, NVV) do { \
    int _buf = (KB) & 1; \
    char* _Pb = _buf ? Pbase1 : Pbase0; \
    int _kn = ((KB) + 1) & 63; \
    if (isS) { \
      f32x4 S[4]; \
      _Pragma("unroll") \
      for (int nt = 0; nt < 4; ++nt) { \
        f32x4 s_ = MFMA16(aql, KH[nt], zf); \
        s_ = MFMA16(aqh, KL[nt], s_); \
        s_ = MFMA16(aqh, KH[nt], s_); \
        S[nt] = s_; \
      } \
      LOADK(NKH, NKL, _kn); \
      LOADV(NVV, _kn); \
      float sc[4]; \
      bool upd = false; \
      _Pragma("unroll") \
      for (int r = 0; r < 4; ++r) { \
        float v = fmaxf(fmaxf(S[0][r], S[1][r]), fmaxf(S[2][r], S[3][r])); \
        DPP_MAX16(v); \
        bool u = v > m[r] + 8.0f;                /* defer-max, P <= 2^8 */ \
        upd |= u; \
        float mn = u ? v : m[r]; \
        sc[r] = __builtin_amdgcn_exp2f(m[r] - mn); \
        m[r] = mn; \
      } \
      bool anyupd = __any((int)upd); \
      short pb[4][4]; \
      float rsum[4]; \
      _Pragma("unroll") \
      for (int r = 0; r < 4; ++r) { \
        float acc = 0.f; \
        _Pragma("unroll") \
        for (int nt = 0; nt < 4; ++nt) { \
          float p = __builtin_amdgcn_exp2f(S[nt][r] - m[r]); \
          acc += p; \
          pb[nt][r] = f2bf(p); \
        } \
        rsum[r] = acc; \
      } \
      _Pragma("unroll") \
      for (int r = 0; r < 4; ++r) { \
        float v = rsum[r]; \
        DPP_SUM16(v); \
        l[r] = l[r] * sc[r] + v; \
      } \
      _Pragma("unroll") \
      for (int nt = 0; nt < 4; ++nt) \
        _Pragma("unroll") \
        for (int r = 0; r < 4; ++r) { \
          int qloc = wS * 16 + g * 4 + r; \
          int kk = nt * 16 + lr; \
          int off = (qloc * 128 + kk * 2) ^ ((qloc & 7) << 4); \
          *(short*)(_Pb + off) = pb[nt][r]; \
        } \
      if (lr == 0) { \
        _Pragma("unroll") \
        for (int r = 0; r < 4; ++r) \
          sm.lp.scale[_buf][wS * 16 + g * 4 + r] = sc[r]; \
      } \
      if (lane == 0) sm.lp.flags[_buf][wS] = anyupd ? 1 : 0; \
    } else { \
      LOADV(NVV, _kn); \
    } \
    BAR();                                       /* lgkm-only: vmcnt stays out */ \
    int need = sm.lp.flags[_buf][0] | sm.lp.flags[_buf][1]; \
    if (need) { \
      _Pragma("unroll") \
      for (int mi = 0; mi < 2; ++mi) \
        _Pragma("unroll") \
        for (int r = 0; r < 4; ++r) { \
          float s = sm.lp.scale[_buf][mi * 16 + g * 4 + r]; \
          _Pragma("unroll") \
          for (int ci = 0; ci < 2; ++ci) O[mi][ci][r] *= s; \
        } \
    } \
    __builtin_amdgcn_s_setprio(1); \
    _Pragma("unroll") \
    for (int ss = 0; ss < 2; ++ss) { \
      short8 ap[2]; \
      _Pragma("unroll") \
      for (int mi = 0; mi < 2; ++mi) { \
        int row = mi * 16 + lr; \
        int off = (row * 128 + (ss * 32 + g * 8) * 2) ^ ((row & 7) << 4); \
        ap[mi] = *(const short8*)(_Pb + off); \
      } \
      _Pragma("unroll") \
      for (int ci = 0; ci < 2; ++ci) { \
        _Pragma("unroll") \
        for (int mi = 0; mi < 2; ++mi) \
          O[mi][ci] = MFMA16(ap[mi], VV[ss * 2 + ci], O[mi][ci]); \
      } \
    } \
    __builtin_amdgcn_s_setprio(0); \
  } while (0)

  short8 khA[4], klA[4], vA[4], khB[4], klB[4], vB[4];
  if (isS) LOADK(khA, klA, 0);
  LOADV(vA, 0);
  #pragma unroll 1
  for (int kb2 = 0; kb2 < 32; ++kb2) {
    STEP(2 * kb2,     khA, klA, vA, khB, klB, vB);
    STEP(2 * kb2 + 1, khB, klB, vB, khA, klA, vA);
  }
#undef STEP
#undef LOADK
#undef LOADV

  if (isS && lr == 0) {
    #pragma unroll
    for (int r = 0; r < 4; ++r)
      l_lds[wS * 16 + g * 4 + r] = l[r];
  }
  __syncthreads();                               // all P reads done before O reuse
  #pragma unroll
  for (int mi = 0; mi < 2; ++mi)
    #pragma unroll
    for (int ci = 0; ci < 2; ++ci) {
      int ch = cw0 + ci * 16 + lr;
      #pragma unroll
      for (int r = 0; r < 4; ++r)
        sm.O[ch][mi * 16 + g * 4 + r] = O[mi][ci][r];
    }
  __syncthreads();
  int q = t & 31, crow = t >> 5;                 // 512 threads: 16 ch-rows x 32 q
  float linv = 1.0f / l_lds[q];
  const float* xb = x + (size_t)b * CH * NN + q0 + q;
  float* ob = out + (size_t)b * CH * NN + q0 + q;
  #pragma unroll
  for (int oi = 0; oi < 16; ++oi) {
    int ch = crow * 16 + oi;
    ob[(size_t)ch * NN] = sm.O[ch][q] * linv + xb[(size_t)ch * NN];
  }
}

extern "C" void kernel_launch(void* const* d_in, const int* in_sizes, int n_in,
                              void* d_out, int out_size, void* d_ws, size_t ws_size,
                              hipStream_t stream) {
  const float* x  = (const float*)d_in[0];
  const float* wq = (const float*)d_in[1];
  const float* bq = (const float*)d_in[2];
  const float* wk = (const float*)d_in[3];
  const float* bk = (const float*)d_in[4];
  const float* wv = (const float*)d_in[5];
  const float* bv = (const float*)d_in[6];
  char* ws = (char*)d_ws;
  // workspace layout (21,136,640 B total)
  short* xT  = (short*)(ws);                     //  8 MB: (b,n,c) bf16
  short* Qh  = (short*)(ws + 8388608);           //  1 MB: (b,n,32) bf16 hi
  short* Ql  = (short*)(ws + 9437184);           //  1 MB: lo
  short* Kh  = (short*)(ws + 10485760);          //  1 MB
  short* Kl  = (short*)(ws + 11534336);          //  1 MB
  short* Vo  = (short*)(ws + 12582912);          //  8 MB: (b,c,n) bf16
  short* WQb = (short*)(ws + 20971520);
  short* WKb = (short*)(ws + 20987904);
  short* WVb = (short*)(ws + 21004288);
  float* BQ  = (float*)(ws + 21135360);
  float* BK  = (float*)(ws + 21135488);
  float* BV  = (float*)(ws + 21135616);

  prep_x<<<1024, 256, 0, stream>>>(x, xT);
  prep_w<<<64, 256, 0, stream>>>(wq, bq, wk, bk, wv, bv,
                                 WQb, WKb, WVb, BQ, BK, BV);
  proj_kernel<<<1024, 256, 0, stream>>>(xT, WQb, WKb, WVb, BQ, BK, BV,
                                        Qh, Ql, Kh, Kl, Vo);
  attn_kernel<<<512, 512, 0, stream>>>(Qh, Ql, Kh, Kl, Vo, x, (float*)d_out);
}

// Round 12
// 204.389 us; speedup vs baseline: 2.3555x; 2.3555x over previous
//
#include <hip/hip_runtime.h>
#include <hip/hip_bf16.h>
#include <stdint.h>

#define CH 256
#define D8 32
#define NN 4096

typedef __attribute__((ext_vector_type(8))) short short8;
typedef __attribute__((ext_vector_type(4))) short s16x4;
typedef __attribute__((ext_vector_type(4))) float f32x4;

#define MFMA16(a,b,c) __builtin_amdgcn_mfma_f32_16x16x32_bf16(a,b,c,0,0,0)
// lgkm-only barrier: orders LDS P/scale/flags producer->consumer WITHOUT
// draining vmcnt -- K/V register prefetches stay in flight across chunks (T4).
#define BAR() asm volatile("s_waitcnt lgkmcnt(0)\n\ts_barrier" ::: "memory")

static __device__ __forceinline__ short f2bf(float f) {
  union { float f; uint32_t u; } v; v.f = f;
  uint32_t r = v.u + 0x7fffu + ((v.u >> 16) & 1u);
  return (short)(r >> 16);
}
static __device__ __forceinline__ float bf2f(short h) {
  union { float f; uint32_t u; } v; v.u = ((uint32_t)(uint16_t)h) << 16;
  return v.f;
}
static __device__ __forceinline__ int f2i(float f) {
  union { float f; int i; } v; v.f = f; return v.i;
}
static __device__ __forceinline__ float i2f(int i) {
  union { float f; int i; } v; v.i = i; return v.f;
}

// DPP 16-lane-row reductions (VALU latency, replaces 4x ds_bpermute ~40cy each)
#define DPP_MAX16(V) do { \
    V = fmaxf(V, i2f(__builtin_amdgcn_update_dpp(0, f2i(V), 0xB1, 0xf, 0xf, true)));  \
    V = fmaxf(V, i2f(__builtin_amdgcn_update_dpp(0, f2i(V), 0x4E, 0xf, 0xf, true)));  \
    V = fmaxf(V, i2f(__builtin_amdgcn_update_dpp(0, f2i(V), 0x124, 0xf, 0xf, true))); \
    V = fmaxf(V, i2f(__builtin_amdgcn_update_dpp(0, f2i(V), 0x128, 0xf, 0xf, true))); \
  } while (0)
#define DPP_SUM16(V) do { \
    V += i2f(__builtin_amdgcn_update_dpp(0, f2i(V), 0xB1, 0xf, 0xf, true));  \
    V += i2f(__builtin_amdgcn_update_dpp(0, f2i(V), 0x4E, 0xf, 0xf, true));  \
    V += i2f(__builtin_amdgcn_update_dpp(0, f2i(V), 0x124, 0xf, 0xf, true)); \
    V += i2f(__builtin_amdgcn_update_dpp(0, f2i(V), 0x128, 0xf, 0xf, true)); \
  } while (0)

// ---------------- prep_x: x (b,c,n) fp32 -> xT (b,n,c) bf16 ----------------
__global__ __launch_bounds__(256) void prep_x(
    const float* __restrict__ x, short* __restrict__ xT)
{
  int blk = blockIdx.x, t = threadIdx.x;
  int b = blk >> 8, ct = (blk >> 6) & 3, nt = blk & 63;
  __shared__ short T[64][65];                    // +1 pad: conflict-free transpose
  int i0 = t >> 4, j4 = (t & 15) * 4;
  const float* xb = x + ((size_t)b * CH + ct * 64) * NN + nt * 64;
  #pragma unroll
  for (int p = 0; p < 4; ++p) {
    int i = i0 + p * 16;
    float4 v = *(const float4*)(xb + (size_t)i * NN + j4);
    T[i][j4 + 0] = f2bf(v.x); T[i][j4 + 1] = f2bf(v.y);
    T[i][j4 + 2] = f2bf(v.z); T[i][j4 + 3] = f2bf(v.w);
  }
  __syncthreads();
  int n = t & 63, c80 = t >> 6;
  short* xTb = xT + ((size_t)b * NN + nt * 64 + n) * CH + ct * 64;
  #pragma unroll
  for (int p = 0; p < 2; ++p) {
    int c8 = c80 + p * 4;
    short8 v;
    #pragma unroll
    for (int k = 0; k < 8; ++k) v[k] = T[c8 * 8 + k][n];
    *(short8*)(xTb + c8 * 8) = v;
  }
}

// ---------------- prep_w: weight convert (64 blocks) ----------------
__global__ __launch_bounds__(256) void prep_w(
    const float* __restrict__ wq, const float* __restrict__ bq,
    const float* __restrict__ wk, const float* __restrict__ bk,
    const float* __restrict__ wv, const float* __restrict__ bv,
    short* __restrict__ WQb, short* __restrict__ WKb, short* __restrict__ WVb,
    float* __restrict__ BQ, float* __restrict__ BK, float* __restrict__ BV)
{
  int idx = blockIdx.x * 256 + threadIdx.x;
  const float LOG2E = 1.4426950408889634f;       // fold into Q so exp2 == exp
  for (int i = idx; i < D8 * CH; i += 16384) WQb[i] = f2bf(wq[i] * LOG2E);
  for (int i = idx; i < D8 * CH; i += 16384) WKb[i] = f2bf(wk[i]);
  for (int i = idx; i < CH * CH; i += 16384) WVb[i] = f2bf(wv[i]);
  if (idx < D8) { BQ[idx] = bq[idx] * LOG2E; BK[idx] = bk[idx]; }
  if (idx < CH) BV[idx] = bv[idx];
}

// ---------------- proj: 1024 blocks (4/CU), 16 pos/block, 5 tiles/wave, prefetched ----------------
__global__ __launch_bounds__(256) void proj_kernel(
    const short* __restrict__ xT,
    const short* __restrict__ WQb, const short* __restrict__ WKb,
    const short* __restrict__ WVb,
    const float* __restrict__ BQ, const float* __restrict__ BK,
    const float* __restrict__ BV,
    short* __restrict__ Qh, short* __restrict__ Ql,
    short* __restrict__ Kh, short* __restrict__ Kl,
    short* __restrict__ Vo)
{
  int blk = blockIdx.x, t = threadIdx.x;
  int b = blk >> 8, pt = blk & 255;
  int w = t >> 6, lane = t & 63, g = lane >> 4, lr = lane & 15;
  int p0 = pt * 16;
  __shared__ short Vt[4][16][20];

  const short* xrow = xT + ((size_t)b * NN + p0 + lr) * CH + g * 8;
  short8 a[8];
  #pragma unroll
  for (int s = 0; s < 8; ++s) a[s] = *(const short8*)(xrow + s * 32);

  const f32x4 zf = {0.f, 0.f, 0.f, 0.f};

#define WLOAD(DST, TT) do { \
    const short* _W; int _tl; \
    if ((TT) < 2)      { _W = WQb; _tl = (TT); } \
    else if ((TT) < 4) { _W = WKb; _tl = (TT) - 2; } \
    else               { _W = WVb; _tl = (TT) - 4; } \
    _Pragma("unroll") \
    for (int s = 0; s < 8; ++s) \
      DST[s] = *(const short8*)(_W + (size_t)(_tl * 16 + lr) * CH + s * 32 + g * 8); \
  } while (0)

#define WCOMP(CUR, TT) do { \
    int _tloc; const float* _Bs; \
    if ((TT) < 2)      { _Bs = BQ; _tloc = (TT); } \
    else if ((TT) < 4) { _Bs = BK; _tloc = (TT) - 2; } \
    else               { _Bs = BV; _tloc = (TT) - 4; } \
    f32x4 acc = zf; \
    _Pragma("unroll") \
    for (int s = 0; s < 8; ++s) acc = MFMA16(a[s], CUR[s], acc); \
    int o = _tloc * 16 + lr; \
    float bias = _Bs[o]; \
    if ((TT) < 4) { \
      short* Oh = ((TT) < 2) ? Qh : Kh; \
      short* Ol = ((TT) < 2) ? Ql : Kl; \
      _Pragma("unroll") \
      for (int r = 0; r < 4; ++r) { \
        int pos = p0 + g * 4 + r; \
        float val = acc[r] + bias; \
        short hi = f2bf(val); \
        Oh[((size_t)b * NN + pos) * D8 + o] = hi; \
        Ol[((size_t)b * NN + pos) * D8 + o] = f2bf(val - bf2f(hi)); \
      } \
    } else { \
      _Pragma("unroll") \
      for (int r = 0; r < 4; ++r) \
        Vt[w][lr][g * 4 + r] = f2bf(acc[r] + bias); \
      int row = lane >> 2, c4 = (lane & 3) * 4; \
      s16x4 vv = *(const s16x4*)&Vt[w][row][c4]; \
      *(s16x4*)(Vo + ((size_t)b * CH + _tloc * 16 + row) * NN + p0 + c4) = vv; \
    } \
  } while (0)

  int t0 = w * 5;
  short8 bA[8], bB[8];
  WLOAD(bA, t0);
  WLOAD(bB, t0 + 1); WCOMP(bA, t0);
  WLOAD(bA, t0 + 2); WCOMP(bB, t0 + 1);
  WLOAD(bB, t0 + 3); WCOMP(bA, t0 + 2);
  WLOAD(bA, t0 + 4); WCOMP(bB, t0 + 3);
  WCOMP(bA, t0 + 4);
#undef WLOAD
#undef WCOMP
}

// -------- attn: r6 structure (119us known-good) + DPP softmax + lgkm-only BAR --------
// 64 q/block, grid 256 (1 blk/CU). waves 0-3: S(16q)+PV(32ch); waves 4-7: PV-only(32ch).
__global__ __launch_bounds__(512) void attn_kernel(
    const short* __restrict__ Qh, const short* __restrict__ Ql,
    const short* __restrict__ Kh, const short* __restrict__ Kl,
    const short* __restrict__ V, const float* __restrict__ x,
    float* __restrict__ out)
{
  int blk = blockIdx.x, t = threadIdx.x;
  // XCD swizzle: 2 XCDs per batch -> per-batch K+V stay L2-resident
  int xcd = blk & 7, idx = blk >> 3;
  int b = xcd >> 1;
  int qt = ((xcd & 1) << 5) + idx;               // 0..63
  int q0 = qt * 64;
  int w = t >> 6, lane = t & 63, g = lane >> 4, lr = lane & 15;
  int wS = w & 3;
  bool isS = (w < 4);
  int cw0 = w * 32;                              // 8 waves x 32 channels

  union Smem {
    struct {
      short P[2][64 * 64];                       // double-buffered, XOR-swizzled
      float scale[2][64];
      int   flags[2][4];
    } lp;
    float O[CH][67];                             // epilogue transpose buffer
  };
  __shared__ Smem sm;
  __shared__ float l_lds[64];

  const short* Qhb = Qh + (size_t)b * NN * D8;
  const short* Qlb = Ql + (size_t)b * NN * D8;
  const short* Khb = Kh + (size_t)b * NN * D8;
  const short* Klb = Kl + (size_t)b * NN * D8;
  const short* Vb = V + (size_t)b * CH * NN;

  short8 aqh, aql;
  if (isS) {
    aqh = *(const short8*)(Qhb + (size_t)(q0 + wS * 16 + lr) * D8 + g * 8);
    aql = *(const short8*)(Qlb + (size_t)(q0 + wS * 16 + lr) * D8 + g * 8);
  }

  const f32x4 zf = {0.f, 0.f, 0.f, 0.f};
  f32x4 O[4][2];                                 // 64q x 32ch per wave
  #pragma unroll
  for (int i = 0; i < 4; ++i)
    #pragma unroll
    for (int j = 0; j < 2; ++j) O[i][j] = zf;
  float m[4] = {-INFINITY, -INFINITY, -INFINITY, -INFINITY};
  float l[4] = {0.f, 0.f, 0.f, 0.f};

  char* Pbase0 = (char*)&sm.lp.P[0][0];
  char* Pbase1 = (char*)&sm.lp.P[1][0];

#define LOADK(KH, KL, KIDX) do { \
    int _k0 = ((KIDX) & 63) * 64; \
    _Pragma("unroll") \
    for (int _nt = 0; _nt < 4; ++_nt) { \
      size_t _off = (size_t)(_k0 + _nt * 16 + lr) * D8 + g * 8; \
      KH[_nt] = *(const short8*)(Khb + _off); \
      KL[_nt] = *(const short8*)(Klb + _off); \
    } \
  } while (0)

#define LOADV(VV, KIDX) do { \
    int _k0 = ((KIDX) & 63) * 64; \
    _Pragma("unroll") \
    for (int _ss = 0; _ss < 2; ++_ss) \
      _Pragma("unroll") \
      for (int _ci = 0; _ci < 2; ++_ci) \
        VV[_ss * 2 + _ci] = *(const short8*)(Vb + \
            (size_t)(cw0 + _ci * 16 + lr) * NN + _k0 + _ss * 32 + g * 8); \
  } while (0)

  // STEP: S waves compute chunk KB + publish; all waves prefetch next; BAR;
  // all 8 waves PV-consume chunk KB from regs VV. (r6 flow, DPP + lgkm BAR.)
#define STEP(KB, KH, KL, VV, NKH, NKL, NVV) do { \
    int _buf = (KB) & 1; \
    char* _Pb = _buf ? Pbase1 : Pbase0; \
    int _kn = ((KB) + 1) & 63; \
    if (isS) { \
      f32x4 S[4]; \
      _Pragma("unroll") \
      for (int nt = 0; nt < 4; ++nt) { \
        f32x4 s_ = MFMA16(aql, KH[nt], zf); \
        s_ = MFMA16(aqh, KL[nt], s_); \
        s_ = MFMA16(aqh, KH[nt], s_); \
        S[nt] = s_; \
      } \
      LOADK(NKH, NKL, _kn); \
      LOADV(NVV, _kn); \
      float sc[4]; \
      bool upd = false; \
      _Pragma("unroll") \
      for (int r = 0; r < 4; ++r) { \
        float v = fmaxf(fmaxf(S[0][r], S[1][r]), fmaxf(S[2][r], S[3][r])); \
        DPP_MAX16(v); \
        bool u = v > m[r] + 8.0f;                /* defer-max, P <= 2^8 */ \
        upd |= u; \
        float mn = u ? v : m[r]; \
        sc[r] = __builtin_amdgcn_exp2f(m[r] - mn); \
        m[r] = mn; \
      } \
      bool anyupd = __any((int)upd); \
      short pb[4][4]; \
      float rsum[4]; \
      _Pragma("unroll") \
      for (int r = 0; r < 4; ++r) { \
        float acc = 0.f; \
        _Pragma("unroll") \
        for (int nt = 0; nt < 4; ++nt) { \
          float p = __builtin_amdgcn_exp2f(S[nt][r] - m[r]); \
          acc += p; \
          pb[nt][r] = f2bf(p); \
        } \
        rsum[r] = acc; \
      } \
      _Pragma("unroll") \
      for (int r = 0; r < 4; ++r) { \
        float v = rsum[r]; \
        DPP_SUM16(v); \
        l[r] = l[r] * sc[r] + v; \
      } \
      _Pragma("unroll") \
      for (int nt = 0; nt < 4; ++nt) \
        _Pragma("unroll") \
        for (int r = 0; r < 4; ++r) { \
          int qloc = wS * 16 + g * 4 + r; \
          int kk = nt * 16 + lr; \
          int off = (qloc * 128 + kk * 2) ^ ((qloc & 7) << 4); \
          *(short*)(_Pb + off) = pb[nt][r]; \
        } \
      if (lr == 0) { \
        _Pragma("unroll") \
        for (int r = 0; r < 4; ++r) \
          sm.lp.scale[_buf][wS * 16 + g * 4 + r] = sc[r]; \
      } \
      if (lane == 0) sm.lp.flags[_buf][wS] = anyupd ? 1 : 0; \
    } else { \
      LOADV(NVV, _kn); \
    } \
    BAR();                                       /* lgkm-only: vmcnt stays out */ \
    int need = sm.lp.flags[_buf][0] | sm.lp.flags[_buf][1] | \
               sm.lp.flags[_buf][2] | sm.lp.flags[_buf][3]; \
    if (need) { \
      _Pragma("unroll") \
      for (int mi = 0; mi < 4; ++mi) \
        _Pragma("unroll") \
        for (int r = 0; r < 4; ++r) { \
          float s = sm.lp.scale[_buf][mi * 16 + g * 4 + r]; \
          _Pragma("unroll") \
          for (int ci = 0; ci < 2; ++ci) O[mi][ci][r] *= s; \
        } \
    } \
    __builtin_amdgcn_s_setprio(1); \
    _Pragma("unroll") \
    for (int ss = 0; ss < 2; ++ss) { \
      short8 ap[4]; \
      _Pragma("unroll") \
      for (int mi = 0; mi < 4; ++mi) { \
        int row = mi * 16 + lr; \
        int off = (row * 128 + (ss * 32 + g * 8) * 2) ^ ((row & 7) << 4); \
        ap[mi] = *(const short8*)(_Pb + off); \
      } \
      _Pragma("unroll") \
      for (int ci = 0; ci < 2; ++ci) { \
        _Pragma("unroll") \
        for (int mi = 0; mi < 4; ++mi) \
          O[mi][ci] = MFMA16(ap[mi], VV[ss * 2 + ci], O[mi][ci]); \
      } \
    } \
    __builtin_amdgcn_s_setprio(0); \
  } while (0)

  short8 khA[4], klA[4], vA[4], khB[4], klB[4], vB[4];
  if (isS) LOADK(khA, klA, 0);
  LOADV(vA, 0);
  #pragma unroll 1
  for (int kb2 = 0; kb2 < 32; ++kb2) {
    STEP(2 * kb2,     khA, klA, vA, khB, klB, vB);
    STEP(2 * kb2 + 1, khB, klB, vB, khA, klA, vA);
  }
#undef STEP
#undef LOADK
#undef LOADV

  if (isS && lr == 0) {
    #pragma unroll
    for (int r = 0; r < 4; ++r)
      l_lds[wS * 16 + g * 4 + r] = l[r];
  }
  __syncthreads();                               // full drain once: P done before O reuse
  #pragma unroll
  for (int mi = 0; mi < 4; ++mi)
    #pragma unroll
    for (int ci = 0; ci < 2; ++ci) {
      int ch = cw0 + ci * 16 + lr;
      #pragma unroll
      for (int r = 0; r < 4; ++r)
        sm.O[ch][mi * 16 + g * 4 + r] = O[mi][ci][r];
    }
  __syncthreads();
  int q = t & 63, crow = t >> 6;                 // 512 threads: 8 ch-rows x 64 q
  float linv = 1.0f / l_lds[q];
  const float* xb = x + (size_t)b * CH * NN + q0 + q;
  float* ob = out + (size_t)b * CH * NN + q0 + q;
  #pragma unroll
  for (int oi = 0; oi < 32; ++oi) {
    int ch = crow * 32 + oi;
    ob[(size_t)ch * NN] = sm.O[ch][q] * linv + xb[(size_t)ch * NN];
  }
}

extern "C" void kernel_launch(void* const* d_in, const int* in_sizes, int n_in,
                              void* d_out, int out_size, void* d_ws, size_t ws_size,
                              hipStream_t stream) {
  const float* x  = (const float*)d_in[0];
  const float* wq = (const float*)d_in[1];
  const float* bq = (const float*)d_in[2];
  const float* wk = (const float*)d_in[3];
  const float* bk = (const float*)d_in[4];
  const float* wv = (const float*)d_in[5];
  const float* bv = (const float*)d_in[6];
  char* ws = (char*)d_ws;
  // workspace layout (21,136,640 B total)
  short* xT  = (short*)(ws);                     //  8 MB: (b,n,c) bf16
  short* Qh  = (short*)(ws + 8388608);           //  1 MB: (b,n,32) bf16 hi
  short* Ql  = (short*)(ws + 9437184);           //  1 MB: lo
  short* Kh  = (short*)(ws + 10485760);          //  1 MB
  short* Kl  = (short*)(ws + 11534336);          //  1 MB
  short* Vo  = (short*)(ws + 12582912);          //  8 MB: (b,c,n) bf16
  short* WQb = (short*)(ws + 20971520);
  short* WKb = (short*)(ws + 20987904);
  short* WVb = (short*)(ws + 21004288);
  float* BQ  = (float*)(ws + 21135360);
  float* BK  = (float*)(ws + 21135488);
  float* BV  = (float*)(ws + 21135616);

  prep_x<<<1024, 256, 0, stream>>>(x, xT);
  prep_w<<<64, 256, 0, stream>>>(wq, bq, wk, bk, wv, bv,
                                 WQb, WKb, WVb, BQ, BK, BV);
  proj_kernel<<<1024, 256, 0, stream>>>(xT, WQb, WKb, WVb, BQ, BK, BV,
                                        Qh, Ql, Kh, Kl, Vo);
  attn_kernel<<<256, 512, 0, stream>>>(Qh, Ql, Kh, Kl, Vo, x, (float*)d_out);
}